// Round 12
// baseline (2072.915 us; speedup 1.0000x reference)
//
#include <hip/hip_runtime.h>
#include <hip/hip_bf16.h>

#define EPS 1e-5f

// ---------------------------------------------------------------------------
// MFMA-based ST-GCN. Layouts:
//   x   : (N,2,256,18) external
//   U   : (n, CO, 18, TIN) bf16       pre-A-mix channel-GEMM output
//   G   : (n, CO, 18, Tr=TIN+16) bf16 post A-mix/BN1/ReLU, 8-half zero guards
//   B*  : (n, CO, 18, TOUT) bf16      block output (R12: bf16, was fp32)
//   Xt  : (n, 18, T, CO) bf16         c-innermost smoothed output
// Conv: MFMA 16x16x32 bf16, K=(c, tap padded 9->16, k innermost) -> lane K-run
// = 8 consecutive t of G, direct global loads, no LDS; K-loop prefetched (R11).
// R12: NC = floor((ws-weights)/per_n) with ragged chunks (was pow2 halving;
// ws measured in [179,354) MB so 32 was forced); bf16 B1/B2 + no smooth
// write-back cuts per-n 5.49->4.31 MB -> NC>=40 guaranteed, conv grids
// scale with NC for latency hiding. fp32 accumulation everywhere.
// ---------------------------------------------------------------------------

typedef __attribute__((ext_vector_type(8))) short bf16x8;
typedef __attribute__((ext_vector_type(4))) float f32x4;
typedef __attribute__((ext_vector_type(4))) unsigned u32x4;

__device__ __forceinline__ unsigned short f2bf(float f) {
  unsigned u = __builtin_bit_cast(unsigned, f);
  u = (u + 0x7FFFu + ((u >> 16) & 1u)) >> 16;  // RNE, finite inputs
  return (unsigned short)u;
}
__device__ __forceinline__ float bf2f(unsigned short h) {
  unsigned u = (unsigned)h << 16;
  return __builtin_bit_cast(float, u);
}

// --------------------------- weight prep -----------------------------------

__global__ __launch_bounds__(256, 4) void k_transpose(
    const float* __restrict__ in, float* __restrict__ out, int rows, int cols) {
  int i = blockIdx.x * 256 + threadIdx.x;
  if (i < rows * cols) {
    int r = i / cols, c = i % cols;
    out[c * rows + r] = in[i];
  }
}

// beta[o] = s2*tb + b2 + rb
__global__ __launch_bounds__(256, 4) void k_beta(
    const float* __restrict__ bn2g, const float* __restrict__ bn2b,
    const float* __restrict__ tb, const float* __restrict__ rb,
    float* __restrict__ beta, int Co) {
  int o = blockIdx.x * 256 + threadIdx.x;
  if (o < Co)
    beta[o] = bn2g[o] * (1.0f / sqrtf(1.0f + EPS)) * tb[o] + bn2b[o] + rb[o];
}

// Conv A pack: out[ot][kc][lane][8], K-chunk = 2c x 16k (k innermost, pad 9->16)
__global__ __launch_bounds__(256, 4) void k_pack_conv(
    const float* __restrict__ tw, const float* __restrict__ bn2g,
    unsigned short* __restrict__ out, int CO) {
  int total = (CO / 16) * (CO / 2) * 512;
  int i = blockIdx.x * 256 + threadIdx.x;
  if (i >= total) return;
  int j = i & 7, lane = (i >> 3) & 63, rest = i >> 9;
  int kc = rest % (CO / 2), ot = rest / (CO / 2);
  int q = lane >> 4, m = lane & 15;
  int c = kc * 2 + (q >> 1), k = (q & 1) * 8 + j, o = ot * 16 + m;
  float val = 0.0f;
  if (k < 9)
    val = tw[((size_t)o * CO + c) * 9 + k] * bn2g[o] * (1.0f / sqrtf(1.0f + EPS));
  out[i] = f2bf(val);
}

// K=c pack (residual rw / channel gw): out[ot][kc][lane][8], c = kc*32+q*8+j
__global__ __launch_bounds__(256, 4) void k_pack_k32(
    const float* __restrict__ W, unsigned short* __restrict__ out, int K, int M) {
  int total = (M / 16) * (K / 32) * 512;
  int i = blockIdx.x * 256 + threadIdx.x;
  if (i >= total) return;
  int j = i & 7, lane = (i >> 3) & 63, rest = i >> 9;
  int kc = rest % (K / 32), ot = rest / (K / 32);
  int q = lane >> 4, m = lane & 15;
  int c = kc * 32 + q * 8 + j, o = ot * 16 + m;
  out[i] = f2bf(W[(size_t)o * K + c]);
}

// --------------------------- block 1 front ---------------------------------
// data_bn + 1x1 (Ci=2) -> U1 (n,64,18,256) bf16; also XB (n,2,18,256) fp32
__global__ __launch_bounds__(256, 4) void k_front1(
    const float* __restrict__ x, const float* __restrict__ dbng,
    const float* __restrict__ dbnb, const float* __restrict__ gw,
    unsigned short* __restrict__ U1, float* __restrict__ xb1) {
  int n = blockIdx.x, t0 = blockIdx.y * 64;
  __shared__ float xb[2 * 64 * 18];  // [c][tt][v]
  const float rs = 1.0f / sqrtf(1.0f + EPS);
  for (int e = threadIdx.x; e < 2304; e += 256) {
    int c = e / 1152, r = e % 1152;  // r = tt*18+v
    int v = r % 18;
    xb[e] = x[(n * 2 + c) * 4608 + t0 * 18 + r] * (dbng[c * 18 + v] * rs) + dbnb[c * 18 + v];
  }
  __syncthreads();
  for (int e = threadIdx.x; e < 2304; e += 256) {
    int c = e / 1152, r = e % 1152;
    int v = r / 64, tt = r % 64;
    xb1[((size_t)(n * 2 + c) * 18 + v) * 256 + t0 + tt] = xb[c * 1152 + tt * 18 + v];
  }
  for (int e = threadIdx.x; e < 64 * 1152; e += 256) {
    int o = e / 1152, r = e % 1152;
    int v = r / 64, tt = r % 64;
    float g0 = gw[o * 2 + 0], g1 = gw[o * 2 + 1];
    U1[((size_t)(n * 64 + o) * 18 + v) * 256 + t0 + tt] =
        f2bf(fmaf(g0, xb[tt * 18 + v], g1 * xb[1152 + tt * 18 + v]));
  }
}

// --------------------------- channel GEMM (MFMA) ---------------------------
// U[n,o,p] = sum_c gw[o,c] * Xt[n,p,c];  p = v*T+t, NP = 18*T (mult of 32)
template <int CI, int CO>
__global__ __launch_bounds__(64, 4) void k_ugemm_m(
    const unsigned short* __restrict__ Xt, const unsigned short* __restrict__ Ag,
    unsigned short* __restrict__ U, int NP) {
  const int n = blockIdx.x;
  const int p0 = blockIdx.y * 32;
  const int otg = blockIdx.z;  // 2 o-tiles of 16
  const int lane = threadIdx.x;
  const int q = lane >> 4, nn = lane & 15;
  constexpr int KC = CI / 32;
  f32x4 acc[2][2] = {};
  const unsigned short* Xn = Xt + (size_t)n * NP * CI;
  for (int kc = 0; kc < KC; kc++) {
    bf16x8 A[2];
#pragma unroll
    for (int i = 0; i < 2; i++)
      A[i] = *(const bf16x8*)(Ag + (((size_t)(otg * 2 + i) * KC + kc) * 64 + lane) * 8);
#pragma unroll
    for (int u = 0; u < 2; u++) {
      bf16x8 B = *(const bf16x8*)(Xn + (size_t)(p0 + u * 16 + nn) * CI + kc * 32 + q * 8);
#pragma unroll
      for (int i = 0; i < 2; i++)
        acc[i][u] = __builtin_amdgcn_mfma_f32_16x16x32_bf16(A[i], B, acc[i][u], 0, 0, 0);
    }
  }
#pragma unroll
  for (int i = 0; i < 2; i++)
#pragma unroll
    for (int u = 0; u < 2; u++) {
      int ob = (otg * 2 + i) * 16 + q * 4;
      int p = p0 + u * 16 + nn;
#pragma unroll
      for (int r = 0; r < 4; r++)
        U[((size_t)n * CO + ob + r) * NP + p] = f2bf(acc[i][u][r]);
    }
}

// --------------------------- A-mix + BN1 + ReLU -> G bf16 ------------------
// one thread per (n,c,t) column of 18 joints; writes guarded bf16 rows.
template <int TIN>
__global__ __launch_bounds__(256, 4) void k_amixg(
    const unsigned short* __restrict__ U, unsigned short* __restrict__ G,
    const float* __restrict__ Amat, const float* __restrict__ gb,
    const float* __restrict__ bn1g, const float* __restrict__ bn1b, int CO) {
  constexpr int Tr = TIN + 16;
  const float rs = 1.0f / sqrtf(1.0f + EPS);
  int idx = blockIdx.x * 256 + threadIdx.x;
  int t = idx & (TIN - 1);
  int row = idx / TIN;        // n*CO + c
  int c = row & (CO - 1);     // CO pow2
  const unsigned short* base = U + (size_t)row * (18 * TIN) + t;
  float u[18];
#pragma unroll
  for (int v = 0; v < 18; v++) u[v] = bf2f(base[(size_t)v * TIN]);
  float s1 = bn1g[c] * rs;
  float b1p = fmaf(s1, gb[c], bn1b[c]);
  unsigned short* gbase = G + (size_t)row * 18 * Tr;
#pragma unroll
  for (int v = 0; v < 18; v++) {
    float z = 0.0f;
#pragma unroll
    for (int w = 0; w < 18; w++) z = fmaf(Amat[v * 18 + w], u[w], z);
    z = fmaf(z, s1, b1p);
    z = z > 0.0f ? z : 0.0f;
    gbase[v * Tr + 8 + t] = f2bf(z);
    if (t < 8) gbase[v * Tr + t] = 0;
    if (t >= TIN - 8) gbase[v * Tr + t + 16] = 0;
  }
}

// --------------------------- fused conv (MFMA, prefetched) -----------------
// Out[o,v,to] = relu( beta[o] + sum_{c,k<9} tw's[o,c,k] G[c,v,S*to+k-4]
//                              + sum_c rw[o,c] Xin[c,v,S*to] )  -> bf16
// one wave per block; OTB o-tiles x TB to-tiles x 2 v per wave.
template <int CIN, int CO, int S, int TIN, int TOUT, int OTB, int TB>
__global__ __launch_bounds__(64, 4) void k_conv(
    const unsigned short* __restrict__ G, const unsigned short* __restrict__ Xt,
    const float* __restrict__ XB, const unsigned short* __restrict__ Ac,
    const unsigned short* __restrict__ Ar, const float* __restrict__ rwT1,
    const float* __restrict__ beta, unsigned short* __restrict__ Out) {
  constexpr int Tr = TIN + 16;
  constexpr int KC = CO / 2;
  constexpr int KCR = (CIN >= 32) ? CIN / 32 : 0;
  constexpr int OT2 = CO / (16 * OTB);
  const int n = blockIdx.x;
  const int to_base = blockIdx.y * (16 * TB);
  const int z = blockIdx.z;
  const int otg = z % OT2;
  const int v0 = (z / OT2) * 2;
  const int lane = threadIdx.x;
  const int q = lane >> 4, nn = lane & 15;
  const int cq = q >> 1, kh = q & 1;

  f32x4 acc[OTB][TB][2] = {};

  const unsigned* Gu = (const unsigned*)G;
  size_t h_tu[TB][2];
#pragma unroll
  for (int tb = 0; tb < TB; tb++)
#pragma unroll
    for (int u = 0; u < 2; u++) {
      int t0h = S * (to_base + tb * 16 + nn) - 4 + kh * 8;
      h_tu[tb][u] = ((size_t)n * CO + cq) * (18 * Tr) + (size_t)(v0 + u) * Tr + 8 +
                    (size_t)(long)t0h;
    }

  const unsigned short* Acp = Ac + ((size_t)otg * OTB * KC * 64 + lane) * 8;

  auto loadA = [&](int kc, bf16x8* A) {
#pragma unroll
    for (int i = 0; i < OTB; i++)
      A[i] = *(const bf16x8*)(Acp + ((size_t)i * KC + kc) * 512);
  };
  auto loadB = [&](int kc, bf16x8 (*B)[2]) {
#pragma unroll
    for (int tb = 0; tb < TB; tb++)
#pragma unroll
      for (int u = 0; u < 2; u++) {
        size_t h = h_tu[tb][u] + (size_t)kc * (2 * 18 * Tr);
        union { u32x4 d4; unsigned d[4]; bf16x8 v; } bb;
        if (S == 2) {
          bb.d4 = *(const u32x4*)(Gu + (h >> 1));  // h even for S=2
        } else {
          const unsigned* p = Gu + (h >> 1);
          u32x4 dd = *(const u32x4*)p;
          unsigned d4 = p[4];
          if (h & 1) {
            bb.d[0] = (dd.x >> 16) | (dd.y << 16); bb.d[1] = (dd.y >> 16) | (dd.z << 16);
            bb.d[2] = (dd.z >> 16) | (dd.w << 16); bb.d[3] = (dd.w >> 16) | (d4 << 16);
          } else {
            bb.d4 = dd;
          }
        }
        B[tb][u] = bb.v;
      }
  };

  bf16x8 Acur[OTB], Bcur[TB][2];
  loadA(0, Acur);
  loadB(0, Bcur);
  for (int kc = 0; kc < KC; kc++) {
    bf16x8 Anx[OTB], Bnx[TB][2];
    const int kn = (kc + 1 < KC) ? kc + 1 : kc;  // last iter: harmless reload
    loadA(kn, Anx);
    loadB(kn, Bnx);
#pragma unroll
    for (int i = 0; i < OTB; i++)
#pragma unroll
      for (int tb = 0; tb < TB; tb++)
#pragma unroll
        for (int u = 0; u < 2; u++)
          acc[i][tb][u] =
              __builtin_amdgcn_mfma_f32_16x16x32_bf16(Acur[i], Bcur[tb][u], acc[i][tb][u],
                                                      0, 0, 0);
#pragma unroll
    for (int i = 0; i < OTB; i++) Acur[i] = Anx[i];
#pragma unroll
    for (int tb = 0; tb < TB; tb++)
#pragma unroll
      for (int u = 0; u < 2; u++) Bcur[tb][u] = Bnx[tb][u];
  }

  if (CIN >= 32) {
    for (int kcr = 0; kcr < KCR; kcr++) {
      bf16x8 A[OTB];
#pragma unroll
      for (int i = 0; i < OTB; i++)
        A[i] = *(const bf16x8*)(Ar + (((size_t)(otg * OTB + i) * KCR + kcr) * 64 + lane) * 8);
#pragma unroll
      for (int tb = 0; tb < TB; tb++)
#pragma unroll
        for (int u = 0; u < 2; u++) {
          int t = S * (to_base + tb * 16 + nn);
          bf16x8 B = *(const bf16x8*)(Xt + (((size_t)n * 18 + v0 + u) * TIN + t) * CIN +
                                      kcr * 32 + q * 8);
#pragma unroll
          for (int i = 0; i < OTB; i++)
            acc[i][tb][u] =
                __builtin_amdgcn_mfma_f32_16x16x32_bf16(A[i], B, acc[i][tb][u], 0, 0, 0);
        }
    }
  } else {
#pragma unroll
    for (int ci = 0; ci < 2; ci++) {
#pragma unroll
      for (int tb = 0; tb < TB; tb++)
#pragma unroll
        for (int u = 0; u < 2; u++) {
          float xv =
              XB[(((size_t)n * 2 + ci) * 18 + v0 + u) * TIN + S * (to_base + tb * 16 + nn)];
#pragma unroll
          for (int i = 0; i < OTB; i++) {
            const float4 w4 = *(const float4*)&rwT1[ci * CO + (otg * OTB + i) * 16 + q * 4];
            acc[i][tb][u][0] = fmaf(w4.x, xv, acc[i][tb][u][0]);
            acc[i][tb][u][1] = fmaf(w4.y, xv, acc[i][tb][u][1]);
            acc[i][tb][u][2] = fmaf(w4.z, xv, acc[i][tb][u][2]);
            acc[i][tb][u][3] = fmaf(w4.w, xv, acc[i][tb][u][3]);
          }
        }
    }
  }

#pragma unroll
  for (int i = 0; i < OTB; i++) {
    int ob = (otg * OTB + i) * 16 + q * 4;
    const float4 bt = *(const float4*)&beta[ob];
#pragma unroll
    for (int tb = 0; tb < TB; tb++)
#pragma unroll
      for (int u = 0; u < 2; u++) {
        int v = v0 + u, to = to_base + tb * 16 + nn;
#pragma unroll
        for (int r = 0; r < 4; r++) {
          float val = acc[i][tb][u][r] + ((const float*)&bt)[r];
          Out[(((size_t)n * CO + ob + r) * 18 + v) * TOUT + to] =
              f2bf(val > 0.0f ? val : 0.0f);
        }
      }
  }
}

// ------------- EMA smooth (bf16 in) -> bf16 transposed emission only -------
// grid (nc, 18, CO/64); block 64. X (n,CO,18,T) bf16 read-only; Xt written.
__global__ __launch_bounds__(64) void k_smooth2(
    const unsigned short* __restrict__ X, unsigned short* __restrict__ Xt,
    int CO, int T) {
  __shared__ float tile[64 * 33];
  int n = blockIdx.x, v = blockIdx.y, c0 = blockIdx.z * 64;
  int tid = threadIdx.x;
  float s = 0.0f;
  for (int tc = 0; tc < T; tc += 32) {
    for (int e = tid; e < 64 * 32; e += 64) {
      int cc = e >> 5, tt = e & 31;
      tile[cc * 33 + tt] = bf2f(X[((size_t)(n * CO + c0 + cc) * 18 + v) * T + tc + tt]);
    }
    __syncthreads();
    float* row = &tile[tid * 33];
    int start = 0;
    if (tc == 0) { s = row[0]; start = 1; }
    for (int tt = start; tt < 32; tt++) {
      s = fmaf(0.85f, s, 0.15f * row[tt]);
      row[tt] = s;
    }
    // each thread emits its own row (channel c0+tid) -> no barrier needed here
    for (int it = 0; it < 32; it++)
      Xt[((size_t)(n * 18 + v) * T + tc + it) * CO + c0 + tid] = f2bf(tile[tid * 33 + it]);
    __syncthreads();
  }
}

// in-place EMA on bf16 rows (block 3); rows contiguous length T.
__global__ __launch_bounds__(64) void k_smooth(unsigned short* __restrict__ X, int T) {
  __shared__ float tile[64 * 33];
  size_t r0 = (size_t)blockIdx.x * 64;
  float s = 0.0f;
  for (int tc = 0; tc < T; tc += 32) {
    for (int e = threadIdx.x; e < 64 * 32; e += 64) {
      int r = e >> 5, tt = e & 31;
      tile[r * 33 + tt] = bf2f(X[(r0 + r) * T + tc + tt]);
    }
    __syncthreads();
    float* row = &tile[threadIdx.x * 33];
    int start = 0;
    if (tc == 0) { s = row[0]; start = 1; }
    for (int tt = start; tt < 32; tt++) {
      s = fmaf(0.85f, s, 0.15f * row[tt]);
      row[tt] = s;
    }
    __syncthreads();
    for (int e = threadIdx.x; e < 64 * 32; e += 64) {
      int r = e >> 5, tt = e & 31;
      X[(r0 + r) * T + tc + tt] = f2bf(tile[r * 33 + tt]);
    }
    __syncthreads();
  }
}

// mean over (v,t)=1152 then 10-way FC.  H:(nc,256,18,64) bf16
__global__ __launch_bounds__(256, 4) void k_poolfc(
    const unsigned short* __restrict__ H, const float* __restrict__ fcw,
    const float* __restrict__ fcb, float* __restrict__ out) {
  int n = blockIdx.x;
  __shared__ float pool[256];
  const unsigned short* row = H + (size_t)(n * 256 + threadIdx.x) * 1152;
  float s = 0.0f;
  for (int i = 0; i < 1152; i += 8) {
    u32x4 d = *(const u32x4*)(row + i);
#pragma unroll
    for (int k = 0; k < 4; k++) {
      unsigned dv = ((const unsigned*)&d)[k];
      s += __builtin_bit_cast(float, dv << 16);
      s += __builtin_bit_cast(float, dv & 0xFFFF0000u);
    }
  }
  pool[threadIdx.x] = s * (1.0f / 1152.0f);
  __syncthreads();
  if (threadIdx.x < 10) {
    float a = fcb[threadIdx.x];
    for (int c = 0; c < 256; c++) a = fmaf(fcw[threadIdx.x * 256 + c], pool[c], a);
    out[n * 10 + threadIdx.x] = a;
  }
}

extern "C" void kernel_launch(void* const* d_in, const int* in_sizes, int n_in,
                              void* d_out, int out_size, void* d_ws, size_t ws_size,
                              hipStream_t stream) {
  const float* x    = (const float*)d_in[0];
  const float* Amat = (const float*)d_in[1];
  const float* dbng = (const float*)d_in[2];
  const float* dbnb = (const float*)d_in[3];
  const float* gw1 = (const float*)d_in[4];   const float* gb1 = (const float*)d_in[5];
  const float* bn1g1 = (const float*)d_in[6]; const float* bn1b1 = (const float*)d_in[7];
  const float* tw1 = (const float*)d_in[8];   const float* tb1 = (const float*)d_in[9];
  const float* bn2g1 = (const float*)d_in[10]; const float* bn2b1 = (const float*)d_in[11];
  const float* rw1 = (const float*)d_in[12];  const float* rb1 = (const float*)d_in[13];
  const float* gw2 = (const float*)d_in[14];  const float* gb2 = (const float*)d_in[15];
  const float* bn1g2 = (const float*)d_in[16]; const float* bn1b2 = (const float*)d_in[17];
  const float* tw2 = (const float*)d_in[18];  const float* tb2 = (const float*)d_in[19];
  const float* bn2g2 = (const float*)d_in[20]; const float* bn2b2 = (const float*)d_in[21];
  const float* rw2 = (const float*)d_in[22];  const float* rb2 = (const float*)d_in[23];
  const float* gw3 = (const float*)d_in[24];  const float* gb3 = (const float*)d_in[25];
  const float* bn1g3 = (const float*)d_in[26]; const float* bn1b3 = (const float*)d_in[27];
  const float* tw3 = (const float*)d_in[28];  const float* tb3 = (const float*)d_in[29];
  const float* bn2g3 = (const float*)d_in[30]; const float* bn2b3 = (const float*)d_in[31];
  const float* rw3 = (const float*)d_in[32];  const float* rb3 = (const float*)d_in[33];
  const float* fcw = (const float*)d_in[34];  const float* fcb = (const float*)d_in[35];
  (void)in_sizes; (void)n_in; (void)out_size;

  // ---- weights region at ws base ----
  float* f = (float*)d_ws;
  float* rwT1  = f;             // 128
  float* beta1 = rwT1 + 128;    // 64
  float* beta2 = beta1 + 64;    // 128
  float* beta3 = beta2 + 128;   // 256
  // pad to 1024 floats
  unsigned short* H = (unsigned short*)(f + 1024);
  unsigned short* Ac1 = H;                 // 65536
  unsigned short* Ac2 = Ac1 + 65536;       // 262144
  unsigned short* Ac3 = Ac2 + 262144;      // 1048576
  unsigned short* Ar2 = Ac3 + 1048576;     // 8192
  unsigned short* Ar3 = Ar2 + 8192;        // 32768
  unsigned short* Ag2 = Ar3 + 32768;       // 8192
  unsigned short* Ag3 = Ag2 + 8192;        // 32768
  const size_t WOFFB = 4096 + 1458176ULL * 2;  // 2,920,448 bytes (16B aligned)

  // ---- NC = floor((ws - weights)/per_n), ragged chunks ----
  // per-n bytes: U bf16 1,179,648 + B1 bf16 589,824 + B2 bf16 589,824
  //            + XB fp32 36,864 + G bf16 1,327,104 + Xt bf16 589,824 = 4,313,088
  const size_t PERN = 4313088ULL;
  long long avail = (long long)ws_size - (long long)WOFFB - 256;
  int NC = (avail > 0) ? (int)(avail / (long long)PERN) : 1;
  if (NC > 128) NC = 128;
  if (NC < 1) NC = 1;
  char* wb = (char*)d_ws;
  unsigned short* U  = (unsigned short*)(wb + WOFFB);
  unsigned short* B1 = (unsigned short*)(wb + WOFFB + (size_t)NC * 1179648);
  unsigned short* B2 = B1 + (size_t)NC * 294912;
  float* XB = (float*)((char*)B2 + (size_t)NC * 589824);
  unsigned short* G  = (unsigned short*)((char*)XB + (size_t)NC * 36864);
  unsigned short* Xt = (unsigned short*)((char*)G + (size_t)NC * 1327104);

  // ---- weight prep (idempotent) ----
  k_transpose<<<1, 256, 0, stream>>>(rw1, rwT1, 64, 2);
  k_beta<<<1, 256, 0, stream>>>(bn2g1, bn2b1, tb1, rb1, beta1, 64);
  k_beta<<<1, 256, 0, stream>>>(bn2g2, bn2b2, tb2, rb2, beta2, 128);
  k_beta<<<1, 256, 0, stream>>>(bn2g3, bn2b3, tb3, rb3, beta3, 256);
  k_pack_conv<<<256, 256, 0, stream>>>(tw1, bn2g1, Ac1, 64);
  k_pack_conv<<<1024, 256, 0, stream>>>(tw2, bn2g2, Ac2, 128);
  k_pack_conv<<<4096, 256, 0, stream>>>(tw3, bn2g3, Ac3, 256);
  k_pack_k32<<<32, 256, 0, stream>>>(rw2, Ar2, 64, 128);
  k_pack_k32<<<128, 256, 0, stream>>>(rw3, Ar3, 128, 256);
  k_pack_k32<<<32, 256, 0, stream>>>(gw2, Ag2, 64, 128);
  k_pack_k32<<<128, 256, 0, stream>>>(gw3, Ag3, 128, 256);

  // ---- network per N-chunk (ragged) ----
  for (int n0 = 0; n0 < 128; n0 += NC) {
    const int nc = (128 - n0 < NC) ? 128 - n0 : NC;
    // block 1
    k_front1<<<dim3(nc, 4), 256, 0, stream>>>(
        x + (size_t)n0 * 9216, dbng, dbnb, gw1, U, XB);
    k_amixg<256><<<nc * 64, 256, 0, stream>>>(U, G, Amat, gb1, bn1g1, bn1b1, 64);
    k_conv<2, 64, 1, 256, 256, 4, 2><<<dim3(nc, 8, 9), 64, 0, stream>>>(
        G, nullptr, XB, Ac1, nullptr, rwT1, beta1, B1);
    k_smooth2<<<dim3(nc, 18, 1), 64, 0, stream>>>(B1, Xt, 64, 256);
    // block 2
    k_ugemm_m<64, 128><<<dim3(nc, 144, 4), 64, 0, stream>>>(Xt, Ag2, U, 4608);
    k_amixg<256><<<nc * 128, 256, 0, stream>>>(U, G, Amat, gb2, bn1g2, bn1b2, 128);
    k_conv<64, 128, 2, 256, 128, 4, 2><<<dim3(nc, 4, 18), 64, 0, stream>>>(
        G, Xt, nullptr, Ac2, Ar2, nullptr, beta2, B2);
    k_smooth2<<<dim3(nc, 18, 2), 64, 0, stream>>>(B2, Xt, 128, 128);
    // block 3 (output reuses B1)
    k_ugemm_m<128, 256><<<dim3(nc, 72, 8), 64, 0, stream>>>(Xt, Ag3, U, 2304);
    k_amixg<128><<<nc * 128, 256, 0, stream>>>(U, G, Amat, gb3, bn1g3, bn1b3, 256);
    k_conv<128, 256, 2, 128, 64, 4, 2><<<dim3(nc, 2, 36), 64, 0, stream>>>(
        G, Xt, nullptr, Ac3, Ar3, nullptr, beta3, B1);
    k_smooth<<<nc * 72, 64, 0, stream>>>(B1, 64);
    // head
    k_poolfc<<<nc, 256, 0, stream>>>(B1, fcw, fcb, (float*)d_out + (size_t)n0 * 10);
  }
}

// Round 13
// 1787.050 us; speedup vs baseline: 1.1600x; 1.1600x over previous
//
#include <hip/hip_runtime.h>
#include <hip/hip_bf16.h>

#define EPS 1e-5f

// ---------------------------------------------------------------------------
// MFMA ST-GCN, R13: A-mix commuted BEFORE the channel GEMM.
//   x   : (N,2,256,18) external
//   G   : (n, CO, 18, Tr=TIN+16) bf16  post GraphConv/BN1/ReLU, 8-half guards
//   B*  : (n, CO, 18, TOUT) bf16       block outputs
//   Xt  : (n, 18, T, CO) bf16          c-innermost smoothed output
//   Xm  : (n, 18, T, CO) bf16          A-mixed Xt (over v)
// Pipeline/block: smooth2->Xt ; amixX (v-mix on CIN channels, half of CO) ;
// ugemmG (1x1 GEMM + BN1 + ReLU + guard-zeroing -> G, U eliminated) ;
// conv (MFMA, tap-padded K, prefetch depth-1, reads G + Xt residual).
// NC = min(48, floor(avail/3.72MB)) -- 48*3.72 = 179 MB stays L3-resident
// (R12's NC=77/332MB blew L3: FETCH 38->383MB). fp32 accumulation everywhere.
// ---------------------------------------------------------------------------

typedef __attribute__((ext_vector_type(8))) short bf16x8;
typedef __attribute__((ext_vector_type(4))) float f32x4;
typedef __attribute__((ext_vector_type(4))) unsigned u32x4;

__device__ __forceinline__ unsigned short f2bf(float f) {
  unsigned u = __builtin_bit_cast(unsigned, f);
  u = (u + 0x7FFFu + ((u >> 16) & 1u)) >> 16;  // RNE, finite inputs
  return (unsigned short)u;
}
__device__ __forceinline__ float bf2f(unsigned short h) {
  unsigned u = (unsigned)h << 16;
  return __builtin_bit_cast(float, u);
}

// --------------------------- weight prep -----------------------------------

__global__ __launch_bounds__(256, 4) void k_transpose(
    const float* __restrict__ in, float* __restrict__ out, int rows, int cols) {
  int i = blockIdx.x * 256 + threadIdx.x;
  if (i < rows * cols) {
    int r = i / cols, c = i % cols;
    out[c * rows + r] = in[i];
  }
}

// beta[o] = s2*tb + b2 + rb
__global__ __launch_bounds__(256, 4) void k_beta(
    const float* __restrict__ bn2g, const float* __restrict__ bn2b,
    const float* __restrict__ tb, const float* __restrict__ rb,
    float* __restrict__ beta, int Co) {
  int o = blockIdx.x * 256 + threadIdx.x;
  if (o < Co)
    beta[o] = bn2g[o] * (1.0f / sqrtf(1.0f + EPS)) * tb[o] + bn2b[o] + rb[o];
}

// s1[o] = bn1g*rs ; b1p[o] = s1*gb + bn1b   (BN1 fused into ugemmG epilogue)
__global__ __launch_bounds__(256, 4) void k_s1b1(
    const float* __restrict__ bn1g, const float* __restrict__ bn1b,
    const float* __restrict__ gb, float* __restrict__ s1v,
    float* __restrict__ b1p, int Co) {
  int o = blockIdx.x * 256 + threadIdx.x;
  if (o < Co) {
    float s1 = bn1g[o] * (1.0f / sqrtf(1.0f + EPS));
    s1v[o] = s1;
    b1p[o] = fmaf(s1, gb[o], bn1b[o]);
  }
}

// Conv A pack: out[ot][kc][lane][8], K-chunk = 2c x 16k (k innermost, pad 9->16)
__global__ __launch_bounds__(256, 4) void k_pack_conv(
    const float* __restrict__ tw, const float* __restrict__ bn2g,
    unsigned short* __restrict__ out, int CO) {
  int total = (CO / 16) * (CO / 2) * 512;
  int i = blockIdx.x * 256 + threadIdx.x;
  if (i >= total) return;
  int j = i & 7, lane = (i >> 3) & 63, rest = i >> 9;
  int kc = rest % (CO / 2), ot = rest / (CO / 2);
  int q = lane >> 4, m = lane & 15;
  int c = kc * 2 + (q >> 1), k = (q & 1) * 8 + j, o = ot * 16 + m;
  float val = 0.0f;
  if (k < 9)
    val = tw[((size_t)o * CO + c) * 9 + k] * bn2g[o] * (1.0f / sqrtf(1.0f + EPS));
  out[i] = f2bf(val);
}

// K=c pack (residual rw / channel gw): out[ot][kc][lane][8], c = kc*32+q*8+j
__global__ __launch_bounds__(256, 4) void k_pack_k32(
    const float* __restrict__ W, unsigned short* __restrict__ out, int K, int M) {
  int total = (M / 16) * (K / 32) * 512;
  int i = blockIdx.x * 256 + threadIdx.x;
  if (i >= total) return;
  int j = i & 7, lane = (i >> 3) & 63, rest = i >> 9;
  int kc = rest % (K / 32), ot = rest / (K / 32);
  int q = lane >> 4, m = lane & 15;
  int c = kc * 32 + q * 8 + j, o = ot * 16 + m;
  out[i] = f2bf(W[(size_t)o * K + c]);
}

// --------------------------- block 1 front (fused) -------------------------
// data_bn -> A-mix (2ch) -> 1x1 (2->64) -> BN1+ReLU -> G1 bf16 (+guards);
// also XB (n,2,18,256) fp32 for conv1 residual.
__global__ __launch_bounds__(256, 4) void k_front1g(
    const float* __restrict__ x, const float* __restrict__ dbng,
    const float* __restrict__ dbnb, const float* __restrict__ Amat,
    const float* __restrict__ gw, const float* __restrict__ gb,
    const float* __restrict__ bn1g, const float* __restrict__ bn1b,
    unsigned short* __restrict__ G1, float* __restrict__ xb1) {
  int n = blockIdx.x, t0 = blockIdx.y * 64;
  __shared__ float xb[2304];  // [c][tt][v]
  __shared__ float xm[2304];  // A-mixed
  __shared__ float As[324];
  const float rs = 1.0f / sqrtf(1.0f + EPS);
  for (int e = threadIdx.x; e < 324; e += 256) As[e] = Amat[e];
  for (int e = threadIdx.x; e < 2304; e += 256) {
    int c = e / 1152, r = e % 1152;  // r = tt*18+v
    int v = r % 18;
    xb[e] = x[(n * 2 + c) * 4608 + t0 * 18 + r] * (dbng[c * 18 + v] * rs) + dbnb[c * 18 + v];
  }
  __syncthreads();
  for (int e = threadIdx.x; e < 2304; e += 256) {
    int c = e / 1152, r = e % 1152;
    int v = r / 64, tt = r % 64;
    xb1[((size_t)(n * 2 + c) * 18 + v) * 256 + t0 + tt] = xb[c * 1152 + tt * 18 + v];
  }
  for (int e = threadIdx.x; e < 2304; e += 256) {
    int c = e / 1152, r = e % 1152;
    int tt = r / 18, v = r % 18;
    const float* xr = &xb[c * 1152 + tt * 18];
    float z = 0.0f;
#pragma unroll
    for (int w = 0; w < 18; w++) z = fmaf(As[v * 18 + w], xr[w], z);
    xm[e] = z;
  }
  __syncthreads();
  for (int e = threadIdx.x; e < 64 * 1152; e += 256) {
    int o = e / 1152, r = e % 1152;
    int v = r / 64, tt = r % 64;
    float s1 = bn1g[o] * rs;
    float g0 = gw[o * 2 + 0] * s1, g1 = gw[o * 2 + 1] * s1;
    float bp = fmaf(s1, gb[o], bn1b[o]);
    // NOTE: xm is [c][tt][v] with r-index tt*18+v
    float z = fmaf(g0, xm[tt * 18 + v], fmaf(g1, xm[1152 + tt * 18 + v], bp));
    z = z > 0.0f ? z : 0.0f;
    int t = t0 + tt;
    size_t row = ((size_t)(n * 64 + o) * 18 + v) * 272;
    G1[row + 8 + t] = f2bf(z);
    if (t < 8) G1[row + t] = 0;
    if (t >= 248) G1[row + t + 16] = 0;
  }
}

// --------------------------- A-mix on Xt -----------------------------------
// Xm[n,v,t,c] = sum_w A[v][w] Xt[n,w,t,c]
template <int CO, int T>
__global__ __launch_bounds__(256, 4) void k_amixX(
    const unsigned short* __restrict__ Xt, unsigned short* __restrict__ Xm,
    const float* __restrict__ Amat) {
  int idx = blockIdx.x * 256 + threadIdx.x;
  int c = idx & (CO - 1);
  int t = (idx / CO) & (T - 1);
  int n = idx / (CO * T);
  const size_t stride = (size_t)T * CO;
  const unsigned short* bp = Xt + (size_t)n * 18 * stride + (size_t)t * CO + c;
  unsigned short* op = Xm + (size_t)n * 18 * stride + (size_t)t * CO + c;
  float xs[18];
#pragma unroll
  for (int w = 0; w < 18; w++) xs[w] = bf2f(bp[w * stride]);
#pragma unroll
  for (int v = 0; v < 18; v++) {
    float z = 0.0f;
#pragma unroll
    for (int w = 0; w < 18; w++) z = fmaf(Amat[v * 18 + w], xs[w], z);
    op[v * stride] = f2bf(z);
  }
}

// --------------------------- channel GEMM -> G (MFMA) ----------------------
// G[n,o,v,8+t] = relu( s1[o] * (sum_c gw[o,c] Xm[n,v,t,c]) + b1p[o] ), +guards
template <int CI, int CO, int TIN>
__global__ __launch_bounds__(64, 4) void k_ugemmG(
    const unsigned short* __restrict__ Xm, const unsigned short* __restrict__ Ag,
    const float* __restrict__ s1v, const float* __restrict__ b1p,
    unsigned short* __restrict__ G) {
  constexpr int NP = 18 * TIN;
  constexpr int Tr = TIN + 16;
  const int n = blockIdx.x;
  const int p0 = blockIdx.y * 32;
  const int otg = blockIdx.z;  // 2 o-tiles of 16
  const int lane = threadIdx.x;
  const int q = lane >> 4, nn = lane & 15;
  constexpr int KC = CI / 32;
  const int v = p0 / TIN;
  const int tb = p0 % TIN;
  f32x4 acc[2][2] = {};
  const unsigned short* Xn = Xm + (size_t)n * NP * CI;
  for (int kc = 0; kc < KC; kc++) {
    bf16x8 A[2];
#pragma unroll
    for (int i = 0; i < 2; i++)
      A[i] = *(const bf16x8*)(Ag + (((size_t)(otg * 2 + i) * KC + kc) * 64 + lane) * 8);
#pragma unroll
    for (int u = 0; u < 2; u++) {
      bf16x8 B = *(const bf16x8*)(Xn + (size_t)(p0 + u * 16 + nn) * CI + kc * 32 + q * 8);
#pragma unroll
      for (int i = 0; i < 2; i++)
        acc[i][u] = __builtin_amdgcn_mfma_f32_16x16x32_bf16(A[i], B, acc[i][u], 0, 0, 0);
    }
  }
#pragma unroll
  for (int i = 0; i < 2; i++) {
    int ob = (otg * 2 + i) * 16 + q * 4;
    const float4 s4 = *(const float4*)&s1v[ob];
    const float4 b4 = *(const float4*)&b1p[ob];
#pragma unroll
    for (int u = 0; u < 2; u++) {
      int t = tb + u * 16 + nn;
#pragma unroll
      for (int r = 0; r < 4; r++) {
        float z = fmaf(acc[i][u][r], ((const float*)&s4)[r], ((const float*)&b4)[r]);
        z = z > 0.0f ? z : 0.0f;
        G[((size_t)(n * CO + ob + r) * 18 + v) * Tr + 8 + t] = f2bf(z);
      }
    }
  }
  // guard zeroing: this block owns o in [otg*32, otg*32+32) for joint v
  if (tb == 0) {
    int oh = otg * 32 + (lane >> 1), j0 = (lane & 1) * 4;
    size_t row = ((size_t)(n * CO + oh) * 18 + v) * Tr;
#pragma unroll
    for (int j = 0; j < 4; j++) G[row + j0 + j] = 0;
  }
  if (tb == TIN - 32) {
    int oh = otg * 32 + (lane >> 1), j0 = (lane & 1) * 4;
    size_t row = ((size_t)(n * CO + oh) * 18 + v) * Tr + 8 + TIN;
#pragma unroll
    for (int j = 0; j < 4; j++) G[row + j0 + j] = 0;
  }
}

// --------------------------- fused conv (MFMA, prefetched) -----------------
template <int CIN, int CO, int S, int TIN, int TOUT, int OTB, int TB>
__global__ __launch_bounds__(64, 4) void k_conv(
    const unsigned short* __restrict__ G, const unsigned short* __restrict__ Xt,
    const float* __restrict__ XB, const unsigned short* __restrict__ Ac,
    const unsigned short* __restrict__ Ar, const float* __restrict__ rwT1,
    const float* __restrict__ beta, unsigned short* __restrict__ Out) {
  constexpr int Tr = TIN + 16;
  constexpr int KC = CO / 2;
  constexpr int KCR = (CIN >= 32) ? CIN / 32 : 0;
  constexpr int OT2 = CO / (16 * OTB);
  const int n = blockIdx.x;
  const int to_base = blockIdx.y * (16 * TB);
  const int z = blockIdx.z;
  const int otg = z % OT2;
  const int v0 = (z / OT2) * 2;
  const int lane = threadIdx.x;
  const int q = lane >> 4, nn = lane & 15;
  const int cq = q >> 1, kh = q & 1;

  f32x4 acc[OTB][TB][2] = {};

  const unsigned* Gu = (const unsigned*)G;
  size_t h_tu[TB][2];
#pragma unroll
  for (int tb = 0; tb < TB; tb++)
#pragma unroll
    for (int u = 0; u < 2; u++) {
      int t0h = S * (to_base + tb * 16 + nn) - 4 + kh * 8;
      h_tu[tb][u] = ((size_t)n * CO + cq) * (18 * Tr) + (size_t)(v0 + u) * Tr + 8 +
                    (size_t)(long)t0h;
    }

  const unsigned short* Acp = Ac + ((size_t)otg * OTB * KC * 64 + lane) * 8;

  auto loadA = [&](int kc, bf16x8* A) {
#pragma unroll
    for (int i = 0; i < OTB; i++)
      A[i] = *(const bf16x8*)(Acp + ((size_t)i * KC + kc) * 512);
  };
  auto loadB = [&](int kc, bf16x8 (*B)[2]) {
#pragma unroll
    for (int tb = 0; tb < TB; tb++)
#pragma unroll
      for (int u = 0; u < 2; u++) {
        size_t h = h_tu[tb][u] + (size_t)kc * (2 * 18 * Tr);
        union { u32x4 d4; unsigned d[4]; bf16x8 v; } bb;
        if (S == 2) {
          bb.d4 = *(const u32x4*)(Gu + (h >> 1));  // h even for S=2
        } else {
          const unsigned* p = Gu + (h >> 1);
          u32x4 dd = *(const u32x4*)p;
          unsigned d4 = p[4];
          if (h & 1) {
            bb.d[0] = (dd.x >> 16) | (dd.y << 16); bb.d[1] = (dd.y >> 16) | (dd.z << 16);
            bb.d[2] = (dd.z >> 16) | (dd.w << 16); bb.d[3] = (dd.w >> 16) | (d4 << 16);
          } else {
            bb.d4 = dd;
          }
        }
        B[tb][u] = bb.v;
      }
  };

  bf16x8 Acur[OTB], Bcur[TB][2];
  loadA(0, Acur);
  loadB(0, Bcur);
  for (int kc = 0; kc < KC; kc++) {
    bf16x8 Anx[OTB], Bnx[TB][2];
    const int kn = (kc + 1 < KC) ? kc + 1 : kc;  // last iter: harmless reload
    loadA(kn, Anx);
    loadB(kn, Bnx);
#pragma unroll
    for (int i = 0; i < OTB; i++)
#pragma unroll
      for (int tb = 0; tb < TB; tb++)
#pragma unroll
        for (int u = 0; u < 2; u++)
          acc[i][tb][u] =
              __builtin_amdgcn_mfma_f32_16x16x32_bf16(Acur[i], Bcur[tb][u], acc[i][tb][u],
                                                      0, 0, 0);
#pragma unroll
    for (int i = 0; i < OTB; i++) Acur[i] = Anx[i];
#pragma unroll
    for (int tb = 0; tb < TB; tb++)
#pragma unroll
      for (int u = 0; u < 2; u++) Bcur[tb][u] = Bnx[tb][u];
  }

  if (CIN >= 32) {
    for (int kcr = 0; kcr < KCR; kcr++) {
      bf16x8 A[OTB];
#pragma unroll
      for (int i = 0; i < OTB; i++)
        A[i] = *(const bf16x8*)(Ar + (((size_t)(otg * OTB + i) * KCR + kcr) * 64 + lane) * 8);
#pragma unroll
      for (int tb = 0; tb < TB; tb++)
#pragma unroll
        for (int u = 0; u < 2; u++) {
          int t = S * (to_base + tb * 16 + nn);
          bf16x8 B = *(const bf16x8*)(Xt + (((size_t)n * 18 + v0 + u) * TIN + t) * CIN +
                                      kcr * 32 + q * 8);
#pragma unroll
          for (int i = 0; i < OTB; i++)
            acc[i][tb][u] =
                __builtin_amdgcn_mfma_f32_16x16x32_bf16(A[i], B, acc[i][tb][u], 0, 0, 0);
        }
    }
  } else {
#pragma unroll
    for (int ci = 0; ci < 2; ci++) {
#pragma unroll
      for (int tb = 0; tb < TB; tb++)
#pragma unroll
        for (int u = 0; u < 2; u++) {
          float xv =
              XB[(((size_t)n * 2 + ci) * 18 + v0 + u) * TIN + S * (to_base + tb * 16 + nn)];
#pragma unroll
          for (int i = 0; i < OTB; i++) {
            const float4 w4 = *(const float4*)&rwT1[ci * CO + (otg * OTB + i) * 16 + q * 4];
            acc[i][tb][u][0] = fmaf(w4.x, xv, acc[i][tb][u][0]);
            acc[i][tb][u][1] = fmaf(w4.y, xv, acc[i][tb][u][1]);
            acc[i][tb][u][2] = fmaf(w4.z, xv, acc[i][tb][u][2]);
            acc[i][tb][u][3] = fmaf(w4.w, xv, acc[i][tb][u][3]);
          }
        }
    }
  }

#pragma unroll
  for (int i = 0; i < OTB; i++) {
    int ob = (otg * OTB + i) * 16 + q * 4;
    const float4 bt = *(const float4*)&beta[ob];
#pragma unroll
    for (int tb = 0; tb < TB; tb++)
#pragma unroll
      for (int u = 0; u < 2; u++) {
        int v = v0 + u, to = to_base + tb * 16 + nn;
#pragma unroll
        for (int r = 0; r < 4; r++) {
          float val = acc[i][tb][u][r] + ((const float*)&bt)[r];
          Out[(((size_t)n * CO + ob + r) * 18 + v) * TOUT + to] =
              f2bf(val > 0.0f ? val : 0.0f);
        }
      }
  }
}

// ------------- EMA smooth (bf16 in) -> bf16 transposed emission ------------
__global__ __launch_bounds__(64) void k_smooth2(
    const unsigned short* __restrict__ X, unsigned short* __restrict__ Xt,
    int CO, int T) {
  __shared__ float tile[64 * 33];
  int n = blockIdx.x, v = blockIdx.y, c0 = blockIdx.z * 64;
  int tid = threadIdx.x;
  float s = 0.0f;
  for (int tc = 0; tc < T; tc += 32) {
    for (int e = tid; e < 64 * 32; e += 64) {
      int cc = e >> 5, tt = e & 31;
      tile[cc * 33 + tt] = bf2f(X[((size_t)(n * CO + c0 + cc) * 18 + v) * T + tc + tt]);
    }
    __syncthreads();
    float* row = &tile[tid * 33];
    int start = 0;
    if (tc == 0) { s = row[0]; start = 1; }
    for (int tt = start; tt < 32; tt++) {
      s = fmaf(0.85f, s, 0.15f * row[tt]);
      row[tt] = s;
    }
    for (int it = 0; it < 32; it++)
      Xt[((size_t)(n * 18 + v) * T + tc + it) * CO + c0 + tid] = f2bf(tile[tid * 33 + it]);
    __syncthreads();
  }
}

// in-place EMA on bf16 rows (block 3); rows contiguous length T.
__global__ __launch_bounds__(64) void k_smooth(unsigned short* __restrict__ X, int T) {
  __shared__ float tile[64 * 33];
  size_t r0 = (size_t)blockIdx.x * 64;
  float s = 0.0f;
  for (int tc = 0; tc < T; tc += 32) {
    for (int e = threadIdx.x; e < 64 * 32; e += 64) {
      int r = e >> 5, tt = e & 31;
      tile[r * 33 + tt] = bf2f(X[(r0 + r) * T + tc + tt]);
    }
    __syncthreads();
    float* row = &tile[threadIdx.x * 33];
    int start = 0;
    if (tc == 0) { s = row[0]; start = 1; }
    for (int tt = start; tt < 32; tt++) {
      s = fmaf(0.85f, s, 0.15f * row[tt]);
      row[tt] = s;
    }
    __syncthreads();
    for (int e = threadIdx.x; e < 64 * 32; e += 64) {
      int r = e >> 5, tt = e & 31;
      X[(r0 + r) * T + tc + tt] = f2bf(tile[r * 33 + tt]);
    }
    __syncthreads();
  }
}

// mean over (v,t)=1152 then 10-way FC.  H:(nc,256,18,64) bf16
__global__ __launch_bounds__(256, 4) void k_poolfc(
    const unsigned short* __restrict__ H, const float* __restrict__ fcw,
    const float* __restrict__ fcb, float* __restrict__ out) {
  int n = blockIdx.x;
  __shared__ float pool[256];
  const unsigned short* row = H + (size_t)(n * 256 + threadIdx.x) * 1152;
  float s = 0.0f;
  for (int i = 0; i < 1152; i += 8) {
    u32x4 d = *(const u32x4*)(row + i);
#pragma unroll
    for (int k = 0; k < 4; k++) {
      unsigned dv = ((const unsigned*)&d)[k];
      s += __builtin_bit_cast(float, dv << 16);
      s += __builtin_bit_cast(float, dv & 0xFFFF0000u);
    }
  }
  pool[threadIdx.x] = s * (1.0f / 1152.0f);
  __syncthreads();
  if (threadIdx.x < 10) {
    float a = fcb[threadIdx.x];
    for (int c = 0; c < 256; c++) a = fmaf(fcw[threadIdx.x * 256 + c], pool[c], a);
    out[n * 10 + threadIdx.x] = a;
  }
}

extern "C" void kernel_launch(void* const* d_in, const int* in_sizes, int n_in,
                              void* d_out, int out_size, void* d_ws, size_t ws_size,
                              hipStream_t stream) {
  const float* x    = (const float*)d_in[0];
  const float* Amat = (const float*)d_in[1];
  const float* dbng = (const float*)d_in[2];
  const float* dbnb = (const float*)d_in[3];
  const float* gw1 = (const float*)d_in[4];   const float* gb1 = (const float*)d_in[5];
  const float* bn1g1 = (const float*)d_in[6]; const float* bn1b1 = (const float*)d_in[7];
  const float* tw1 = (const float*)d_in[8];   const float* tb1 = (const float*)d_in[9];
  const float* bn2g1 = (const float*)d_in[10]; const float* bn2b1 = (const float*)d_in[11];
  const float* rw1 = (const float*)d_in[12];  const float* rb1 = (const float*)d_in[13];
  const float* gw2 = (const float*)d_in[14];  const float* gb2 = (const float*)d_in[15];
  const float* bn1g2 = (const float*)d_in[16]; const float* bn1b2 = (const float*)d_in[17];
  const float* tw2 = (const float*)d_in[18];  const float* tb2 = (const float*)d_in[19];
  const float* bn2g2 = (const float*)d_in[20]; const float* bn2b2 = (const float*)d_in[21];
  const float* rw2 = (const float*)d_in[22];  const float* rb2 = (const float*)d_in[23];
  const float* gw3 = (const float*)d_in[24];  const float* gb3 = (const float*)d_in[25];
  const float* bn1g3 = (const float*)d_in[26]; const float* bn1b3 = (const float*)d_in[27];
  const float* tw3 = (const float*)d_in[28];  const float* tb3 = (const float*)d_in[29];
  const float* bn2g3 = (const float*)d_in[30]; const float* bn2b3 = (const float*)d_in[31];
  const float* rw3 = (const float*)d_in[32];  const float* rb3 = (const float*)d_in[33];
  const float* fcw = (const float*)d_in[34];  const float* fcb = (const float*)d_in[35];
  (void)in_sizes; (void)n_in; (void)out_size;

  // ---- weights region at ws base ----
  float* f = (float*)d_ws;
  float* rwT1  = f;             // 128
  float* beta1 = rwT1 + 128;    // 64
  float* beta2 = beta1 + 64;    // 128
  float* beta3 = beta2 + 128;   // 256
  float* s1v2  = beta3 + 256;   // 128
  float* b1p2  = s1v2 + 128;    // 128
  float* s1v3  = b1p2 + 128;    // 256
  float* b1p3  = s1v3 + 256;    // 256
  // pad to 2048 floats
  unsigned short* H = (unsigned short*)(f + 2048);
  unsigned short* Ac1 = H;                 // 65536
  unsigned short* Ac2 = Ac1 + 65536;       // 262144
  unsigned short* Ac3 = Ac2 + 262144;      // 1048576
  unsigned short* Ar2 = Ac3 + 1048576;     // 8192
  unsigned short* Ar3 = Ar2 + 8192;        // 32768
  unsigned short* Ag2 = Ar3 + 32768;       // 8192
  unsigned short* Ag3 = Ag2 + 8192;        // 32768
  const size_t WOFFB = 8192 + 1458176ULL * 2;  // 2,924,544 bytes (16B aligned)

  // ---- NC = min(48, floor(avail/per_n)) ----
  // per-n bytes: B1 589824 + B2 589824 + XB 36864 + G 1327104
  //            + Xt 589824 + Xm 589824 = 3,723,264
  const size_t PERN = 3723264ULL;
  long long avail = (long long)ws_size - (long long)WOFFB - 256;
  int NC = (avail > 0) ? (int)(avail / (long long)PERN) : 1;
  if (NC > 48) NC = 48;   // keep chunk working set <= ~180 MB (L3-resident)
  if (NC < 1) NC = 1;
  char* wb = (char*)d_ws;
  unsigned short* B1 = (unsigned short*)(wb + WOFFB);
  unsigned short* B2 = B1 + (size_t)NC * 294912;
  float* XB = (float*)((char*)B2 + (size_t)NC * 589824);
  unsigned short* G  = (unsigned short*)((char*)XB + (size_t)NC * 36864);
  unsigned short* Xt = (unsigned short*)((char*)G + (size_t)NC * 1327104);
  unsigned short* Xm = Xt + (size_t)NC * 294912;

  // ---- weight prep (idempotent) ----
  k_transpose<<<1, 256, 0, stream>>>(rw1, rwT1, 64, 2);
  k_beta<<<1, 256, 0, stream>>>(bn2g1, bn2b1, tb1, rb1, beta1, 64);
  k_beta<<<1, 256, 0, stream>>>(bn2g2, bn2b2, tb2, rb2, beta2, 128);
  k_beta<<<1, 256, 0, stream>>>(bn2g3, bn2b3, tb3, rb3, beta3, 256);
  k_s1b1<<<1, 256, 0, stream>>>(bn1g2, bn1b2, gb2, s1v2, b1p2, 128);
  k_s1b1<<<1, 256, 0, stream>>>(bn1g3, bn1b3, gb3, s1v3, b1p3, 256);
  k_pack_conv<<<256, 256, 0, stream>>>(tw1, bn2g1, Ac1, 64);
  k_pack_conv<<<1024, 256, 0, stream>>>(tw2, bn2g2, Ac2, 128);
  k_pack_conv<<<4096, 256, 0, stream>>>(tw3, bn2g3, Ac3, 256);
  k_pack_k32<<<32, 256, 0, stream>>>(rw2, Ar2, 64, 128);
  k_pack_k32<<<128, 256, 0, stream>>>(rw3, Ar3, 128, 256);
  k_pack_k32<<<32, 256, 0, stream>>>(gw2, Ag2, 64, 128);
  k_pack_k32<<<128, 256, 0, stream>>>(gw3, Ag3, 128, 256);

  // ---- network per N-chunk (ragged) ----
  for (int n0 = 0; n0 < 128; n0 += NC) {
    const int nc = (128 - n0 < NC) ? 128 - n0 : NC;
    // block 1
    k_front1g<<<dim3(nc, 4), 256, 0, stream>>>(
        x + (size_t)n0 * 9216, dbng, dbnb, Amat, gw1, gb1, bn1g1, bn1b1, G, XB);
    k_conv<2, 64, 1, 256, 256, 4, 2><<<dim3(nc, 8, 9), 64, 0, stream>>>(
        G, nullptr, XB, Ac1, nullptr, rwT1, beta1, B1);
    k_smooth2<<<dim3(nc, 18, 1), 64, 0, stream>>>(B1, Xt, 64, 256);
    // block 2
    k_amixX<64, 256><<<nc * 64, 256, 0, stream>>>(Xt, Xm, Amat);
    k_ugemmG<64, 128, 256><<<dim3(nc, 144, 4), 64, 0, stream>>>(
        Xm, Ag2, s1v2, b1p2, G);
    k_conv<64, 128, 2, 256, 128, 4, 2><<<dim3(nc, 4, 18), 64, 0, stream>>>(
        G, Xt, nullptr, Ac2, Ar2, nullptr, beta2, B2);
    k_smooth2<<<dim3(nc, 18, 2), 64, 0, stream>>>(B2, Xt, 128, 128);
    // block 3 (output reuses B1)
    k_amixX<128, 128><<<nc * 64, 256, 0, stream>>>(Xt, Xm, Amat);
    k_ugemmG<128, 256, 128><<<dim3(nc, 72, 8), 64, 0, stream>>>(
        Xm, Ag3, s1v3, b1p3, G);
    k_conv<128, 256, 2, 128, 64, 4, 2><<<dim3(nc, 2, 36), 64, 0, stream>>>(
        G, Xt, nullptr, Ac3, Ar3, nullptr, beta3, B1);
    k_smooth<<<nc * 72, 64, 0, stream>>>(B1, 64);
    // head
    k_poolfc<<<nc, 256, 0, stream>>>(B1, fcw, fcb, (float*)d_out + (size_t)n0 * 10);
  }
}